// Round 17
// baseline (241.682 us; speedup 1.0000x reference)
//
#include <hip/hip_runtime.h>
#include <hip/hip_bf16.h>

typedef __bf16 bf16x8 __attribute__((ext_vector_type(8)));
typedef float f32x4 __attribute__((ext_vector_type(4)));
typedef unsigned short u16;

#define MFMA16(a, b, c) __builtin_amdgcn_mfma_f32_16x16x32_bf16((a), (b), (c), 0, 0, 0)

typedef __attribute__((address_space(1))) void glb_void;
typedef __attribute__((address_space(3))) void lds_void;

// async global->LDS, 16B per lane; LDS dest = wave-uniform base + lane*16
__device__ __forceinline__ void gload16(const void* g, void* l) {
    __builtin_amdgcn_global_load_lds((glb_void*)g, (lds_void*)l, 16, 0, 0);
}

__device__ __forceinline__ float bf2f(u16 h) {
    union { unsigned int u; float f; } v;
    v.u = ((unsigned int)h) << 16;
    return v.f;
}
__device__ __forceinline__ u16 f2bf(float f) {
    union { float f; unsigned int u; } v;
    v.f = f;
    unsigned int r = v.u + 0x7fffu + ((v.u >> 16) & 1u);
    return (u16)(r >> 16);
}
__device__ __forceinline__ float bfround(float f) { return bf2f(f2bf(f)); }
// native RNE f32->bf16 (v_cvt, bit-identical to f2bf for non-NaN) — attn hot loop
__device__ __forceinline__ u16 f2bf_n(float f) {
    union { __bf16 h; u16 u; } t; t.h = (__bf16)f; return t.u;
}
__device__ __forceinline__ float bfrd(float f) { return (float)(__bf16)f; }

// ws layout (u16 elems): [ctl 64][base: xb/ctx 4194304][wqkv_t/wout_t 3145728][Vt 4194304]
// d_out (16 MB f32): stages Qb (8 MB bf16) + Kb (8 MB bf16); final GEMM overwrites with f32.
// Config = verified 227.4us best (r16) + T1 XCD swizzle on qkv/outp (r17):
// dispatch model xcd = linear_bid & 7 (verified r2/r5/r8). outp default map gave each XCD
// 1 B-col + ALL 32 A-panels (8MB > 4MB L2, thrash); remap to 4-by band/XCD -> footprint
// 3MB (L2-resident). qkv: 4-by band/XCD -> 7MB (A-band resident, B streamed once).
// Closed: GEMM BK=64 (r8/r12), attn pad 76 (r13), attn reg-prefetch (r5/r6/r15 — r15
// showed scratch spill: VGPR pinned 56, WRITE_SIZE 8->60MB, rule #20).

// ---- init: probe + bind + MFMA self-test, single 1-block kernel ----
__global__ __launch_bounds__(256) void MultiHeadSelfAttention_11759620456627_init(
    const u16* p0, const u16* p1, const u16* p2, const u16* p3, const u16* p4, const u16* p5,
    int s0, int s1, int s2, int s3, int s4, int s5,
    int n_in, unsigned long long wsbytes, u16* ws) {
    __shared__ unsigned long long sctl[6];
    __shared__ int flagv;
    __shared__ __align__(16) u16 At[512];
    __shared__ __align__(16) u16 Bt2[512];
    const int tid = threadIdx.x;
    if (tid == 0) flagv = 0;
    if (tid < 64) {
        const u16* ptrs[6] = {p0, p1, p2, p3, p4, p5};
        long long szs[6] = {s0, s1, s2, s3, s4, s5};
        int cls[6];
        const u16* xp = 0;
        int xf = 0, ncx = 0, ncw = 0;
        const u16* wp[2] = {0, 0};
        long long wsz[2] = {0, 0};
        int wf[2] = {0, 0};
        const size_t lane = (size_t)tid;
        for (int i = 0; i < 6; ++i) {
            cls[i] = 3;
            if (i >= n_in || ptrs[i] == 0 || szs[i] < 1048576) continue;  // wave-uniform
            u16 a = ptrs[i][lane * 8191 + 1];
            float fa = fabsf(bf2f(a));
            float vb = ((const float*)(const void*)ptrs[i])[lane * 4093 + 1];
            float fb = fabsf(vb);
            const int nmask  = __popcll(__ballot(a == 0 || a == 1 || a == 256 || a == 257 || a == 0x3F80));
            const int plausA = __popcll(__ballot(fa > 0.0005f && fa < 64.0f));
            const int plausB = __popcll(__ballot(fb > 0.0005f && fb < 64.0f));
            const int bigA   = __popcll(__ballot(fa >= 0.125f && fa < 64.0f));
            const int bigB   = __popcll(__ballot(fb >= 0.125f && fb < 64.0f));
            if (nmask >= 60) { cls[i] = 0; continue; }
            const int isf = (plausB > plausA) ? 1 : 0;
            const int big = isf ? bigB : bigA;
            if (big >= 16) { cls[i] = 2; xp = ptrs[i]; xf = isf; ++ncx; }
            else {
                cls[i] = 1;
                if (ncw < 2) { wp[ncw] = ptrs[i]; wsz[ncw] = szs[i]; wf[ncw] = isf; }
                ++ncw;
            }
        }
        if (tid == 0) {
            const u16 *wq = 0, *wo = 0;
            int qf = 0, of = 0, ok = 0;
            if (ncx == 1 && ncw == 2) {
                if (wsz[0] == 3 * wsz[1])      { wq = wp[0]; qf = wf[0]; wo = wp[1]; of = wf[1]; ok = 1; }
                else if (wsz[1] == 3 * wsz[0]) { wq = wp[1]; qf = wf[1]; wo = wp[0]; of = wf[0]; ok = 1; }
            }
            const int wsok = (wsbytes >= 128ull + 23068672ull) ? 1 : 0;
            if (!wsok) ok = 0;
            float code = 0.0f;
            if (!ok) {
                if (!wsok) code = 6144.0f;
                else if (ncx == 1 && ncw == 2) code = 5120.0f;
                else code = 2048.0f + 8.0f * (float)(cls[0] + 4 * cls[1] + 16 * cls[2] + 64 * cls[3]);
            }
            sctl[0] = (unsigned long long)xp;
            sctl[1] = (unsigned long long)wq;
            sctl[2] = (unsigned long long)wo;
            sctl[3] = (unsigned long long)ok;
            sctl[4] = (unsigned long long)(xf | (qf << 1) | (of << 2));
            union { float f; unsigned int u; } cv; cv.f = code;
            sctl[5] = (unsigned long long)cv.u;
        }
    }
    __syncthreads();
    const int okv = (sctl[3] != 0ull);
    if (okv) {   // MFMA self-test (block-uniform gate)
        if (tid < 64)
            for (int i = tid; i < 512; i += 64) {
                int m = i >> 5, k = i & 31;
                At[i]  = f2bf((float)((m * 3 + k) % 7 - 3) * 0.25f);
                Bt2[i] = f2bf((float)((m + 2 * k) % 5 - 2) * 0.25f);
            }
        __syncthreads();
        if (tid < 64) {
            const int l16 = tid & 15, quad = tid >> 4;
            bf16x8 a = *(bf16x8*)&At[l16 * 32 + quad * 8];
            bf16x8 b = *(bf16x8*)&Bt2[l16 * 32 + quad * 8];
            f32x4 c = {0.f, 0.f, 0.f, 0.f};
            c = MFMA16(a, b, c);
            for (int r = 0; r < 4; ++r) {
                const int row = quad * 4 + r, col = l16;
                float ref = 0.f;
                for (int k = 0; k < 32; ++k) ref += bf2f(At[row * 32 + k]) * bf2f(Bt2[col * 32 + k]);
                if (fabsf(c[r] - ref) > 1e-3f) { *(volatile int*)&flagv = 1; }
            }
        }
        __syncthreads();
    }
    if (tid == 0) {
        if (okv && flagv) {
            sctl[3] = 0ull;
            union { float f; unsigned int u; } cv; cv.f = 10240.0f;
            sctl[5] = (unsigned long long)cv.u;
        }
        unsigned long long* ctl = (unsigned long long*)ws;
        for (int i = 0; i < 6; ++i) ctl[i] = sctl[i];
    }
}

// ---- prep: convx (blocks 0..2047, f32 input only) + transpose Wqkv (blocks 2048..2815) ----
__global__ __launch_bounds__(256) void MultiHeadSelfAttention_11759620456627_prep(u16* ws) {
    unsigned long long* ctl = (unsigned long long*)ws;
    if (ctl[3] == 0ull) return;
    __shared__ __align__(16) u16 t[64][72];   // transw path only; pad 72 = 16B-aligned rows
    const int bid = (int)blockIdx.x;
    const int tid = threadIdx.x;
    if (bid < 2048) {   // convx: only needed for f32 input (bf16 read directly by qkv)
        const int xf = (int)(ctl[4] & 1ull);
        if (!xf) return;
        u16* base = ws + 64;
        const float* xp = (const float*)(const void*)ctl[0];
        const size_t i0 = ((size_t)(bid * 256 + tid)) * 8;
        float4 a = *(const float4*)&xp[i0];
        float4 bb = *(const float4*)&xp[i0 + 4];
        union { u16 h[8]; int4 v; } tv;
        tv.h[0] = f2bf(a.x);  tv.h[1] = f2bf(a.y);  tv.h[2] = f2bf(a.z);  tv.h[3] = f2bf(a.w);
        tv.h[4] = f2bf(bb.x); tv.h[5] = f2bf(bb.y); tv.h[6] = f2bf(bb.z); tv.h[7] = f2bf(bb.w);
        *(int4*)&base[i0] = tv.v;
        return;
    }
    // transw0: Wqkv (1024 x 3072) -> wqkv_t (3072 x 1024)
    const int idx = bid - 2048;
    const int bx = idx % 48, by = idx / 48;
    const u16* src = (const u16*)ctl[1];
    const int flag = (int)((ctl[4] >> 1) & 1ull);
    const int C = 3072, R = 1024;
    u16* dst = ws + 64 + 4194304;
    const int r0 = by * 64, c0 = bx * 64;
    for (int i = tid; i < 512; i += 256) {
        const int r = i >> 3, c8 = (i & 7) * 8;
        const size_t o = (size_t)(r0 + r) * C + c0 + c8;
        if (!flag) {
            *(int4*)&t[r][c8] = *(const int4*)&src[o];
        } else {
            const float* sf = (const float*)(const void*)src;
            float4 a = *(const float4*)&sf[o];
            float4 bb = *(const float4*)&sf[o + 4];
            u16* d = &t[r][c8];
            d[0] = f2bf(a.x);  d[1] = f2bf(a.y);  d[2] = f2bf(a.z);  d[3] = f2bf(a.w);
            d[4] = f2bf(bb.x); d[5] = f2bf(bb.y); d[6] = f2bf(bb.z); d[7] = f2bf(bb.w);
        }
    }
    __syncthreads();
    for (int i = tid; i < 512; i += 256) {
        const int r = i >> 3, c8 = (i & 7) * 8;
        union { u16 h[8]; int4 v; } tmp;
#pragma unroll
        for (int j = 0; j < 8; ++j) tmp.h[j] = t[c8 + j][r];
        *(int4*)&dst[(size_t)(c0 + r) * R + r0 + c8] = tmp.v;
    }
}

// ---- transpose Wout (1024x1024) -> wout_t; runs after qkv (reuses wqkv_t region) ----
__global__ __launch_bounds__(256) void MultiHeadSelfAttention_11759620456627_transw(u16* ws) {
    unsigned long long* ctl = (unsigned long long*)ws;
    if (ctl[3] == 0ull) return;
    __shared__ __align__(16) u16 t[64][72];
    const int tid = threadIdx.x;
    const u16* src = (const u16*)ctl[2];
    const int flag = (int)((ctl[4] >> 2) & 1ull);
    const int C = 1024, R = 1024;
    u16* dst = ws + 64 + 4194304;
    const int r0 = blockIdx.y * 64, c0 = blockIdx.x * 64;
    for (int idx = tid; idx < 512; idx += 256) {
        const int r = idx >> 3, c8 = (idx & 7) * 8;
        const size_t o = (size_t)(r0 + r) * C + c0 + c8;
        if (!flag) {
            *(int4*)&t[r][c8] = *(const int4*)&src[o];
        } else {
            const float* sf = (const float*)(const void*)src;
            float4 a = *(const float4*)&sf[o];
            float4 bb = *(const float4*)&sf[o + 4];
            u16* d = &t[r][c8];
            d[0] = f2bf(a.x);  d[1] = f2bf(a.y);  d[2] = f2bf(a.z);  d[3] = f2bf(a.w);
            d[4] = f2bf(bb.x); d[5] = f2bf(bb.y); d[6] = f2bf(bb.z); d[7] = f2bf(bb.w);
        }
    }
    __syncthreads();
    for (int idx = tid; idx < 512; idx += 256) {
        const int r = idx >> 3, c8 = (idx & 7) * 8;
        union { u16 h[8]; int4 v; } tmp;
#pragma unroll
        for (int j = 0; j < 8; ++j) tmp.h[j] = t[c8 + j][r];
        *(int4*)&dst[(size_t)(c0 + r) * R + r0 + c8] = tmp.v;
    }
}

// ---- qkv GEMM (m97, BK=32) + scatter; T1 XCD swizzle: 4-by A-band per XCD ----
__global__ __launch_bounds__(256) void MultiHeadSelfAttention_11759620456627_qkv(u16* out, u16* ws) {
    unsigned long long* ctl = (unsigned long long*)ws;
    if (ctl[3] == 0ull) return;
    __shared__ __align__(16) u16 As[4096];   // 128 x 32 linear (gload_lds contract)
    __shared__ __align__(16) u16 Bs[4096];
    const int xf = (int)(ctl[4] & 1ull);
    const u16* A  = xf ? (ws + 64) : (const u16*)ctl[0];   // bf16 input: read x directly
    const u16* Bt = ws + 64 + 4194304;
    u16* vt = ws + 64 + 7340032;
    u16* qb = out;
    u16* kb = out + 4194304;
    const int K = 1024;
    const int tid = threadIdx.x;
    const int wave = tid >> 6, lane = tid & 63;
    const int quad = lane >> 4, l16 = lane & 15;
    // T1 (bijective): xcd = bid&7 (dispatch model, r2/r5/r8-verified). XCD x owns
    // by in [x*4, x*4+4) (A-band 1MB, L2-resident) x all 24 bx (B streamed).
    const int l = (int)blockIdx.x;                 // 768 blocks, 1D
    const int xcd = l & 7, idx = l >> 3;           // idx in [0,96)
    const int by = xcd * 4 + (idx & 3);            // [0,32)
    const int bx = idx >> 2;                       // [0,24)
    const int m0 = by * 128, n0 = bx * 128;
    const int wr = (wave >> 1) * 64, wc = (wave & 1) * 64;
    f32x4 acc[4][4] = {};
    const int rl = wave * 16 + (lane >> 2), cl = (lane & 3) * 8;
    const u16* a0 = A  + (size_t)(m0 + rl) * K + cl;
    const u16* a1 = A  + (size_t)(m0 + 64 + rl) * K + cl;
    const u16* b0 = Bt + (size_t)(n0 + rl) * K + cl;
    const u16* b1 = Bt + (size_t)(n0 + 64 + rl) * K + cl;
    u16* lA0 = As + wave * 512;
    u16* lA1 = As + 2048 + wave * 512;
    u16* lB0 = Bs + wave * 512;
    u16* lB1 = Bs + 2048 + wave * 512;
    for (int kb2 = 0; kb2 < K; kb2 += 32) {
        gload16(a0 + kb2, lA0);
        gload16(a1 + kb2, lA1);
        gload16(b0 + kb2, lB0);
        gload16(b1 + kb2, lB1);
        __syncthreads();               // drains vmcnt(0): LDS tiles complete
        bf16x8 af[4], bfr[4];
#pragma unroll
        for (int i = 0; i < 4; ++i) af[i] = *(const bf16x8*)&As[(wr + i * 16 + l16) * 32 + quad * 8];
#pragma unroll
        for (int j = 0; j < 4; ++j) bfr[j] = *(const bf16x8*)&Bs[(wc + j * 16 + l16) * 32 + quad * 8];
#pragma unroll
        for (int i = 0; i < 4; ++i)
#pragma unroll
            for (int j = 0; j < 4; ++j) acc[i][j] = MFMA16(af[i], bfr[j], acc[i][j]);
        __syncthreads();
    }
    // scatter: Q,K (BH,L,64) in d_out; V^T (BH,64,L) in ws
#pragma unroll
    for (int i = 0; i < 4; ++i)
#pragma unroll
        for (int j = 0; j < 4; ++j) {
            const int col = n0 + wc + j * 16 + l16;
            const int s = col >> 10, rem = col & 1023;
            const int h = rem >> 6, d = rem & 63;
#pragma unroll
            for (int r = 0; r < 4; ++r) {
                const int row = m0 + wr + i * 16 + quad * 4 + r;
                const int b = row >> 11, ll = row & 2047;
                const int bh = b * 16 + h;
                const u16 val = f2bf(acc[i][j][r]);
                if (s == 0)      qb[((size_t)bh * 2048 + ll) * 64 + d] = val;
                else if (s == 1) kb[((size_t)bh * 2048 + ll) * 64 + d] = val;
                else             vt[((size_t)bh * 64 + d) * 2048 + ll] = val;
            }
        }
}

// ---- flash attention: balanced 4/CU XCD map + setprio, PAD=72 (verified best) ----
__global__ __launch_bounds__(256) void MultiHeadSelfAttention_11759620456627_attn(u16* out, u16* ws) {
    unsigned long long* ctl = (unsigned long long*)ws;
    if (ctl[3] == 0ull) return;
    constexpr int L = 2048, DK = 64, PAD = 72;
    constexpr float C1 = 0.18033688011112042f;   // 0.125 * log2(e)
    constexpr float C2 = -11.541560327111708f;   // -8 * log2(e)
    __shared__ __align__(16) u16 Ks[64 * PAD];
    __shared__ __align__(16) u16 Vs[64 * PAD];
    __shared__ __align__(16) u16 Pl[4 * 16 * PAD];
    u16* base = ws + 64;
    u16* vt   = ws + 64 + 7340032;
    u16* qb   = out;
    u16* kb   = out + 4194304;
    const int tid = threadIdx.x;
    const int wave = tid >> 6, lane = tid & 63;
    const int quad = lane >> 4, l16 = lane & 15;
    const int bid = (int)blockIdx.x;
    const int x = bid & 7, j = bid >> 3;
    const int t = j >> 5, c = j & 31;
    const int bh = x * 4 + t;
    const int c2 = (c + ((t >> 1) << 4)) & 31;
    const int qt = (t & 1) ? c2 : 31 - c2;
    const u16* Qp = qb + (size_t)bh * L * DK;
    const u16* Kp = kb + (size_t)bh * L * DK;
    const u16* Vp = vt + (size_t)bh * DK * L;
    u16* Pw = &Pl[wave * 16 * PAD];
    const int b = bh >> 4, h = bh & 15;
    const int srow = tid >> 3, scol = (tid & 7) * 8;

    const int q0 = qt * 64 + wave * 16;
    const bf16x8 qf0 = *(const bf16x8*)&Qp[(size_t)(q0 + l16) * DK + quad * 8];
    const bf16x8 qf1 = *(const bf16x8*)&Qp[(size_t)(q0 + l16) * DK + quad * 8 + 32];
    f32x4 oacc[4] = {};
    float lpart[4] = {0.f, 0.f, 0.f, 0.f};

    for (int kc = 0; kc <= qt; ++kc) {
        const int k0 = kc * 64;
        __syncthreads();  // Ks/Vs reuse from previous chunk
#pragma unroll
        for (int it = 0; it < 2; ++it) {
            const int r = srow + it * 32;
            *(int4*)&Ks[r * PAD + scol] = *(const int4*)&Kp[(size_t)(k0 + r) * DK + scol];
            *(int4*)&Vs[r * PAD + scol] = *(const int4*)&Vp[(size_t)r * L + k0 + scol];
        }
        __syncthreads();
        const bool maskchunk = (kc == qt);
        f32x4 sacc[4];
        __builtin_amdgcn_s_setprio(1);   // T5: favor MFMA vs co-resident blocks' loads
#pragma unroll
        for (int kt = 0; kt < 4; ++kt) {
            const bf16x8 kf0 = *(const bf16x8*)&Ks[(kt * 16 + l16) * PAD + quad * 8];
            const bf16x8 kf1 = *(const bf16x8*)&Ks[(kt * 16 + l16) * PAD + quad * 8 + 32];
            f32x4 z = {0.f, 0.f, 0.f, 0.f};
            z = MFMA16(qf0, kf0, z);
            sacc[kt] = MFMA16(qf1, kf1, z);
        }
        __builtin_amdgcn_s_setprio(0);
#pragma unroll
        for (int kt = 0; kt < 4; ++kt)
#pragma unroll
            for (int r = 0; r < 4; ++r) {
                float s = bfrd(sacc[kt][r]);           // native cvt (RNE, = bfround)
                if (maskchunk) {
                    const int key = k0 + kt * 16 + l16;
                    const int qrow = q0 + quad * 4 + r;
                    if (key > qrow) s = -3.0e38f;
                }
                const float pv = exp2f(__builtin_fmaf(s, C1, C2));  // exp(s/8 - 8)
                lpart[r] += pv;
                Pw[(quad * 4 + r) * PAD + kt * 16 + l16] = f2bf_n(pv);
            }
        // wave-private P region: lgkmcnt ordering suffices, no barrier
        const bf16x8 pa0 = *(const bf16x8*)&Pw[l16 * PAD + quad * 8];
        const bf16x8 pa1 = *(const bf16x8*)&Pw[l16 * PAD + quad * 8 + 32];
        __builtin_amdgcn_s_setprio(1);
#pragma unroll
        for (int nt = 0; nt < 4; ++nt) {
            const bf16x8 vf0 = *(const bf16x8*)&Vs[(nt * 16 + l16) * PAD + quad * 8];
            const bf16x8 vf1 = *(const bf16x8*)&Vs[(nt * 16 + l16) * PAD + quad * 8 + 32];
            oacc[nt] = MFMA16(pa0, vf0, oacc[nt]);
            oacc[nt] = MFMA16(pa1, vf1, oacc[nt]);
        }
        __builtin_amdgcn_s_setprio(0);
    }
    // reduce l over the 16 lanes holding this row's columns
    float linv[4];
#pragma unroll
    for (int r = 0; r < 4; ++r) {
        float ls = lpart[r];
#pragma unroll
        for (int off = 1; off < 16; off <<= 1) ls += __shfl_xor(ls, off);
        linv[r] = 1.0f / ls;
    }
#pragma unroll
    for (int nt = 0; nt < 4; ++nt)
#pragma unroll
        for (int r = 0; r < 4; ++r) {
            const int q = q0 + quad * 4 + r;
            base[((size_t)b * 2048 + q) * 1024 + h * 64 + nt * 16 + l16] =
                f2bf_n(oacc[nt][r] * linv[r]);
        }
}

// ---- out-proj GEMM (m97, BK=32) -> f32 d_out; T1 XCD swizzle (3MB/XCD, L2-resident) ----
__global__ __launch_bounds__(256) void MultiHeadSelfAttention_11759620456627_outp(u16* out, u16* ws) {
    unsigned long long* ctl = (unsigned long long*)ws;
    const int tid = threadIdx.x;
    if (ctl[3] == 0ull) {  // failure-code fill of f32 d_out (1D grid: bid covers 0..255)
        union { unsigned int u; float f; } cv; cv.u = (unsigned int)ctl[5];
        float* outf = (float*)(void*)out;
        const int bid = blockIdx.y * gridDim.x + blockIdx.x;
        for (int k = 0; k < 64; ++k)
            outf[(size_t)(bid * 256 + tid) + (size_t)k * 65536] = cv.f;
        return;
    }
    __shared__ __align__(16) u16 As[4096];   // 128 x 32 linear
    __shared__ __align__(16) u16 Bs[4096];
    const u16* A  = ws + 64;
    const u16* Bt = ws + 64 + 4194304;
    const int K = 1024;
    const int wave = tid >> 6, lane = tid & 63;
    const int quad = lane >> 4, l16 = lane & 15;
    // T1: default map gave each XCD 1 bx + ALL 32 A-panels (8MB thrash). Remap:
    // XCD x owns by in [x*4,x*4+4) x all 8 bx -> 4xA(1MB)+B(2MB) = 3MB, L2-resident.
    const int l = (int)blockIdx.x;                 // 256 blocks, 1D
    const int xcd = l & 7, idx = l >> 3;           // idx in [0,32)
    const int by = xcd * 4 + (idx & 3);            // [0,32)
    const int bx = idx >> 2;                       // [0,8)
    const int m0 = by * 128, n0 = bx * 128;
    const int wr = (wave >> 1) * 64, wc = (wave & 1) * 64;
    f32x4 acc[4][4] = {};
    const int rl = wave * 16 + (lane >> 2), cl = (lane & 3) * 8;
    const u16* a0 = A  + (size_t)(m0 + rl) * K + cl;
    const u16* a1 = A  + (size_t)(m0 + 64 + rl) * K + cl;
    const u16* b0 = Bt + (size_t)(n0 + rl) * K + cl;
    const u16* b1 = Bt + (size_t)(n0 + 64 + rl) * K + cl;
    u16* lA0 = As + wave * 512;
    u16* lA1 = As + 2048 + wave * 512;
    u16* lB0 = Bs + wave * 512;
    u16* lB1 = Bs + 2048 + wave * 512;
    for (int kb2 = 0; kb2 < K; kb2 += 32) {
        gload16(a0 + kb2, lA0);
        gload16(a1 + kb2, lA1);
        gload16(b0 + kb2, lB0);
        gload16(b1 + kb2, lB1);
        __syncthreads();
        bf16x8 af[4], bfr[4];
#pragma unroll
        for (int i = 0; i < 4; ++i) af[i] = *(const bf16x8*)&As[(wr + i * 16 + l16) * 32 + quad * 8];
#pragma unroll
        for (int j = 0; j < 4; ++j) bfr[j] = *(const bf16x8*)&Bs[(wc + j * 16 + l16) * 32 + quad * 8];
#pragma unroll
        for (int i = 0; i < 4; ++i)
#pragma unroll
            for (int j = 0; j < 4; ++j) acc[i][j] = MFMA16(af[i], bfr[j], acc[i][j]);
        __syncthreads();
    }
    float* outf = (float*)(void*)out;
#pragma unroll
    for (int i = 0; i < 4; ++i)
#pragma unroll
        for (int j = 0; j < 4; ++j) {
            const int col = n0 + wc + j * 16 + l16;
#pragma unroll
            for (int r = 0; r < 4; ++r) {
                const int row = m0 + wr + i * 16 + quad * 4 + r;
                outf[(size_t)row * 1024 + col] = bfround(acc[i][j][r]);
            }
        }
}

extern "C" void kernel_launch(void* const* d_in, const int* in_sizes, int n_in,
                              void* d_out, int out_size, void* d_ws, size_t ws_size,
                              hipStream_t stream) {
    (void)out_size;
    const u16* p[6] = {0, 0, 0, 0, 0, 0};
    int s[6] = {-1, -1, -1, -1, -1, -1};
    for (int i = 0; i < n_in && i < 6; ++i) { p[i] = (const u16*)d_in[i]; s[i] = in_sizes[i]; }
    u16* out = (u16*)d_out;
    u16* ws  = (u16*)d_ws;
    const unsigned long long wsbytes = (unsigned long long)ws_size;

    MultiHeadSelfAttention_11759620456627_init<<<dim3(1, 1), 256, 0, stream>>>(
        p[0], p[1], p[2], p[3], p[4], p[5], s[0], s[1], s[2], s[3], s[4], s[5],
        n_in, wsbytes, ws);
    MultiHeadSelfAttention_11759620456627_prep<<<dim3(2816, 1), 256, 0, stream>>>(ws);
    MultiHeadSelfAttention_11759620456627_qkv<<<dim3(768, 1), 256, 0, stream>>>(out, ws);
    MultiHeadSelfAttention_11759620456627_transw<<<dim3(16, 16), 256, 0, stream>>>(ws);
    MultiHeadSelfAttention_11759620456627_attn<<<dim3(1024, 1), 256, 0, stream>>>(out, ws);
    MultiHeadSelfAttention_11759620456627_outp<<<dim3(256, 1), 256, 0, stream>>>(out, ws);
}

// Round 18
// 227.640 us; speedup vs baseline: 1.0617x; 1.0617x over previous
//
#include <hip/hip_runtime.h>
#include <hip/hip_bf16.h>

typedef __bf16 bf16x8 __attribute__((ext_vector_type(8)));
typedef float f32x4 __attribute__((ext_vector_type(4)));
typedef unsigned short u16;

#define MFMA16(a, b, c) __builtin_amdgcn_mfma_f32_16x16x32_bf16((a), (b), (c), 0, 0, 0)

typedef __attribute__((address_space(1))) void glb_void;
typedef __attribute__((address_space(3))) void lds_void;

// async global->LDS, 16B per lane; LDS dest = wave-uniform base + lane*16
__device__ __forceinline__ void gload16(const void* g, void* l) {
    __builtin_amdgcn_global_load_lds((glb_void*)g, (lds_void*)l, 16, 0, 0);
}

__device__ __forceinline__ float bf2f(u16 h) {
    union { unsigned int u; float f; } v;
    v.u = ((unsigned int)h) << 16;
    return v.f;
}
__device__ __forceinline__ u16 f2bf(float f) {
    union { float f; unsigned int u; } v;
    v.f = f;
    unsigned int r = v.u + 0x7fffu + ((v.u >> 16) & 1u);
    return (u16)(r >> 16);
}
__device__ __forceinline__ float bfround(float f) { return bf2f(f2bf(f)); }
// native RNE f32->bf16 (v_cvt, bit-identical to f2bf for non-NaN) — attn hot loop
__device__ __forceinline__ u16 f2bf_n(float f) {
    union { __bf16 h; u16 u; } t; t.h = (__bf16)f; return t.u;
}
__device__ __forceinline__ float bfrd(float f) { return (float)(__bf16)f; }

// ws layout (u16 elems): [ctl 64][base: xb/ctx 4194304][wqkv_t/wout_t 3145728][Vt 4194304]
// d_out (16 MB f32): stages Qb (8 MB bf16) + Kb (8 MB bf16); final GEMM overwrites with f32.
// FINAL = triple-verified best (r11/r14/r16: 228.2/228.8/227.4us). attn = balanced 4/CU
// XCD map + setprio, PAD=72; GEMM BK=32 [128][32] m97, default block map. Closed by
// measurement: GEMM BK=64 (r8/r12), attn pad 76 (r13), attn reg-prefetch (r5/r6/r15
// scratch-spill), GEMM XCD swizzle (r17: +14us — per-XCD full-B streaming beats nothing).

// ---- init: probe + bind + MFMA self-test, single 1-block kernel ----
__global__ __launch_bounds__(256) void MultiHeadSelfAttention_11759620456627_init(
    const u16* p0, const u16* p1, const u16* p2, const u16* p3, const u16* p4, const u16* p5,
    int s0, int s1, int s2, int s3, int s4, int s5,
    int n_in, unsigned long long wsbytes, u16* ws) {
    __shared__ unsigned long long sctl[6];
    __shared__ int flagv;
    __shared__ __align__(16) u16 At[512];
    __shared__ __align__(16) u16 Bt2[512];
    const int tid = threadIdx.x;
    if (tid == 0) flagv = 0;
    if (tid < 64) {
        const u16* ptrs[6] = {p0, p1, p2, p3, p4, p5};
        long long szs[6] = {s0, s1, s2, s3, s4, s5};
        int cls[6];
        const u16* xp = 0;
        int xf = 0, ncx = 0, ncw = 0;
        const u16* wp[2] = {0, 0};
        long long wsz[2] = {0, 0};
        int wf[2] = {0, 0};
        const size_t lane = (size_t)tid;
        for (int i = 0; i < 6; ++i) {
            cls[i] = 3;
            if (i >= n_in || ptrs[i] == 0 || szs[i] < 1048576) continue;  // wave-uniform
            u16 a = ptrs[i][lane * 8191 + 1];
            float fa = fabsf(bf2f(a));
            float vb = ((const float*)(const void*)ptrs[i])[lane * 4093 + 1];
            float fb = fabsf(vb);
            const int nmask  = __popcll(__ballot(a == 0 || a == 1 || a == 256 || a == 257 || a == 0x3F80));
            const int plausA = __popcll(__ballot(fa > 0.0005f && fa < 64.0f));
            const int plausB = __popcll(__ballot(fb > 0.0005f && fb < 64.0f));
            const int bigA   = __popcll(__ballot(fa >= 0.125f && fa < 64.0f));
            const int bigB   = __popcll(__ballot(fb >= 0.125f && fb < 64.0f));
            if (nmask >= 60) { cls[i] = 0; continue; }
            const int isf = (plausB > plausA) ? 1 : 0;
            const int big = isf ? bigB : bigA;
            if (big >= 16) { cls[i] = 2; xp = ptrs[i]; xf = isf; ++ncx; }
            else {
                cls[i] = 1;
                if (ncw < 2) { wp[ncw] = ptrs[i]; wsz[ncw] = szs[i]; wf[ncw] = isf; }
                ++ncw;
            }
        }
        if (tid == 0) {
            const u16 *wq = 0, *wo = 0;
            int qf = 0, of = 0, ok = 0;
            if (ncx == 1 && ncw == 2) {
                if (wsz[0] == 3 * wsz[1])      { wq = wp[0]; qf = wf[0]; wo = wp[1]; of = wf[1]; ok = 1; }
                else if (wsz[1] == 3 * wsz[0]) { wq = wp[1]; qf = wf[1]; wo = wp[0]; of = wf[0]; ok = 1; }
            }
            const int wsok = (wsbytes >= 128ull + 23068672ull) ? 1 : 0;
            if (!wsok) ok = 0;
            float code = 0.0f;
            if (!ok) {
                if (!wsok) code = 6144.0f;
                else if (ncx == 1 && ncw == 2) code = 5120.0f;
                else code = 2048.0f + 8.0f * (float)(cls[0] + 4 * cls[1] + 16 * cls[2] + 64 * cls[3]);
            }
            sctl[0] = (unsigned long long)xp;
            sctl[1] = (unsigned long long)wq;
            sctl[2] = (unsigned long long)wo;
            sctl[3] = (unsigned long long)ok;
            sctl[4] = (unsigned long long)(xf | (qf << 1) | (of << 2));
            union { float f; unsigned int u; } cv; cv.f = code;
            sctl[5] = (unsigned long long)cv.u;
        }
    }
    __syncthreads();
    const int okv = (sctl[3] != 0ull);
    if (okv) {   // MFMA self-test (block-uniform gate)
        if (tid < 64)
            for (int i = tid; i < 512; i += 64) {
                int m = i >> 5, k = i & 31;
                At[i]  = f2bf((float)((m * 3 + k) % 7 - 3) * 0.25f);
                Bt2[i] = f2bf((float)((m + 2 * k) % 5 - 2) * 0.25f);
            }
        __syncthreads();
        if (tid < 64) {
            const int l16 = tid & 15, quad = tid >> 4;
            bf16x8 a = *(bf16x8*)&At[l16 * 32 + quad * 8];
            bf16x8 b = *(bf16x8*)&Bt2[l16 * 32 + quad * 8];
            f32x4 c = {0.f, 0.f, 0.f, 0.f};
            c = MFMA16(a, b, c);
            for (int r = 0; r < 4; ++r) {
                const int row = quad * 4 + r, col = l16;
                float ref = 0.f;
                for (int k = 0; k < 32; ++k) ref += bf2f(At[row * 32 + k]) * bf2f(Bt2[col * 32 + k]);
                if (fabsf(c[r] - ref) > 1e-3f) { *(volatile int*)&flagv = 1; }
            }
        }
        __syncthreads();
    }
    if (tid == 0) {
        if (okv && flagv) {
            sctl[3] = 0ull;
            union { float f; unsigned int u; } cv; cv.f = 10240.0f;
            sctl[5] = (unsigned long long)cv.u;
        }
        unsigned long long* ctl = (unsigned long long*)ws;
        for (int i = 0; i < 6; ++i) ctl[i] = sctl[i];
    }
}

// ---- prep: convx (blocks 0..2047, f32 input only) + transpose Wqkv (blocks 2048..2815) ----
__global__ __launch_bounds__(256) void MultiHeadSelfAttention_11759620456627_prep(u16* ws) {
    unsigned long long* ctl = (unsigned long long*)ws;
    if (ctl[3] == 0ull) return;
    __shared__ __align__(16) u16 t[64][72];   // transw path only; pad 72 = 16B-aligned rows
    const int bid = (int)blockIdx.x;
    const int tid = threadIdx.x;
    if (bid < 2048) {   // convx: only needed for f32 input (bf16 read directly by qkv)
        const int xf = (int)(ctl[4] & 1ull);
        if (!xf) return;
        u16* base = ws + 64;
        const float* xp = (const float*)(const void*)ctl[0];
        const size_t i0 = ((size_t)(bid * 256 + tid)) * 8;
        float4 a = *(const float4*)&xp[i0];
        float4 bb = *(const float4*)&xp[i0 + 4];
        union { u16 h[8]; int4 v; } tv;
        tv.h[0] = f2bf(a.x);  tv.h[1] = f2bf(a.y);  tv.h[2] = f2bf(a.z);  tv.h[3] = f2bf(a.w);
        tv.h[4] = f2bf(bb.x); tv.h[5] = f2bf(bb.y); tv.h[6] = f2bf(bb.z); tv.h[7] = f2bf(bb.w);
        *(int4*)&base[i0] = tv.v;
        return;
    }
    // transw0: Wqkv (1024 x 3072) -> wqkv_t (3072 x 1024)
    const int idx = bid - 2048;
    const int bx = idx % 48, by = idx / 48;
    const u16* src = (const u16*)ctl[1];
    const int flag = (int)((ctl[4] >> 1) & 1ull);
    const int C = 3072, R = 1024;
    u16* dst = ws + 64 + 4194304;
    const int r0 = by * 64, c0 = bx * 64;
    for (int i = tid; i < 512; i += 256) {
        const int r = i >> 3, c8 = (i & 7) * 8;
        const size_t o = (size_t)(r0 + r) * C + c0 + c8;
        if (!flag) {
            *(int4*)&t[r][c8] = *(const int4*)&src[o];
        } else {
            const float* sf = (const float*)(const void*)src;
            float4 a = *(const float4*)&sf[o];
            float4 bb = *(const float4*)&sf[o + 4];
            u16* d = &t[r][c8];
            d[0] = f2bf(a.x);  d[1] = f2bf(a.y);  d[2] = f2bf(a.z);  d[3] = f2bf(a.w);
            d[4] = f2bf(bb.x); d[5] = f2bf(bb.y); d[6] = f2bf(bb.z); d[7] = f2bf(bb.w);
        }
    }
    __syncthreads();
    for (int i = tid; i < 512; i += 256) {
        const int r = i >> 3, c8 = (i & 7) * 8;
        union { u16 h[8]; int4 v; } tmp;
#pragma unroll
        for (int j = 0; j < 8; ++j) tmp.h[j] = t[c8 + j][r];
        *(int4*)&dst[(size_t)(c0 + r) * R + r0 + c8] = tmp.v;
    }
}

// ---- transpose Wout (1024x1024) -> wout_t; runs after qkv (reuses wqkv_t region) ----
__global__ __launch_bounds__(256) void MultiHeadSelfAttention_11759620456627_transw(u16* ws) {
    unsigned long long* ctl = (unsigned long long*)ws;
    if (ctl[3] == 0ull) return;
    __shared__ __align__(16) u16 t[64][72];
    const int tid = threadIdx.x;
    const u16* src = (const u16*)ctl[2];
    const int flag = (int)((ctl[4] >> 2) & 1ull);
    const int C = 1024, R = 1024;
    u16* dst = ws + 64 + 4194304;
    const int r0 = blockIdx.y * 64, c0 = blockIdx.x * 64;
    for (int idx = tid; idx < 512; idx += 256) {
        const int r = idx >> 3, c8 = (idx & 7) * 8;
        const size_t o = (size_t)(r0 + r) * C + c0 + c8;
        if (!flag) {
            *(int4*)&t[r][c8] = *(const int4*)&src[o];
        } else {
            const float* sf = (const float*)(const void*)src;
            float4 a = *(const float4*)&sf[o];
            float4 bb = *(const float4*)&sf[o + 4];
            u16* d = &t[r][c8];
            d[0] = f2bf(a.x);  d[1] = f2bf(a.y);  d[2] = f2bf(a.z);  d[3] = f2bf(a.w);
            d[4] = f2bf(bb.x); d[5] = f2bf(bb.y); d[6] = f2bf(bb.z); d[7] = f2bf(bb.w);
        }
    }
    __syncthreads();
    for (int idx = tid; idx < 512; idx += 256) {
        const int r = idx >> 3, c8 = (idx & 7) * 8;
        union { u16 h[8]; int4 v; } tmp;
#pragma unroll
        for (int j = 0; j < 8; ++j) tmp.h[j] = t[c8 + j][r];
        *(int4*)&dst[(size_t)(c0 + r) * R + r0 + c8] = tmp.v;
    }
}

// ---- qkv GEMM (m97 structure, BK=32, default block map — proven) + scatter ----
__global__ __launch_bounds__(256) void MultiHeadSelfAttention_11759620456627_qkv(u16* out, u16* ws) {
    unsigned long long* ctl = (unsigned long long*)ws;
    if (ctl[3] == 0ull) return;
    __shared__ __align__(16) u16 As[4096];   // 128 x 32 linear (gload_lds contract)
    __shared__ __align__(16) u16 Bs[4096];
    const int xf = (int)(ctl[4] & 1ull);
    const u16* A  = xf ? (ws + 64) : (const u16*)ctl[0];   // bf16 input: read x directly
    const u16* Bt = ws + 64 + 4194304;
    u16* vt = ws + 64 + 7340032;
    u16* qb = out;
    u16* kb = out + 4194304;
    const int K = 1024;
    const int tid = threadIdx.x;
    const int wave = tid >> 6, lane = tid & 63;
    const int quad = lane >> 4, l16 = lane & 15;
    const int m0 = blockIdx.y * 128, n0 = blockIdx.x * 128;
    const int wr = (wave >> 1) * 64, wc = (wave & 1) * 64;
    f32x4 acc[4][4] = {};
    const int rl = wave * 16 + (lane >> 2), cl = (lane & 3) * 8;
    const u16* a0 = A  + (size_t)(m0 + rl) * K + cl;
    const u16* a1 = A  + (size_t)(m0 + 64 + rl) * K + cl;
    const u16* b0 = Bt + (size_t)(n0 + rl) * K + cl;
    const u16* b1 = Bt + (size_t)(n0 + 64 + rl) * K + cl;
    u16* lA0 = As + wave * 512;
    u16* lA1 = As + 2048 + wave * 512;
    u16* lB0 = Bs + wave * 512;
    u16* lB1 = Bs + 2048 + wave * 512;
    for (int kb2 = 0; kb2 < K; kb2 += 32) {
        gload16(a0 + kb2, lA0);
        gload16(a1 + kb2, lA1);
        gload16(b0 + kb2, lB0);
        gload16(b1 + kb2, lB1);
        __syncthreads();               // drains vmcnt(0): LDS tiles complete
        bf16x8 af[4], bfr[4];
#pragma unroll
        for (int i = 0; i < 4; ++i) af[i] = *(const bf16x8*)&As[(wr + i * 16 + l16) * 32 + quad * 8];
#pragma unroll
        for (int j = 0; j < 4; ++j) bfr[j] = *(const bf16x8*)&Bs[(wc + j * 16 + l16) * 32 + quad * 8];
#pragma unroll
        for (int i = 0; i < 4; ++i)
#pragma unroll
            for (int j = 0; j < 4; ++j) acc[i][j] = MFMA16(af[i], bfr[j], acc[i][j]);
        __syncthreads();
    }
    // scatter: Q,K (BH,L,64) in d_out; V^T (BH,64,L) in ws
#pragma unroll
    for (int i = 0; i < 4; ++i)
#pragma unroll
        for (int j = 0; j < 4; ++j) {
            const int col = n0 + wc + j * 16 + l16;
            const int s = col >> 10, rem = col & 1023;
            const int h = rem >> 6, d = rem & 63;
#pragma unroll
            for (int r = 0; r < 4; ++r) {
                const int row = m0 + wr + i * 16 + quad * 4 + r;
                const int b = row >> 11, l = row & 2047;
                const int bh = b * 16 + h;
                const u16 val = f2bf(acc[i][j][r]);
                if (s == 0)      qb[((size_t)bh * 2048 + l) * 64 + d] = val;
                else if (s == 1) kb[((size_t)bh * 2048 + l) * 64 + d] = val;
                else             vt[((size_t)bh * 64 + d) * 2048 + l] = val;
            }
        }
}

// ---- flash attention: balanced 4/CU XCD map + setprio, PAD=72 (verified best) ----
__global__ __launch_bounds__(256) void MultiHeadSelfAttention_11759620456627_attn(u16* out, u16* ws) {
    unsigned long long* ctl = (unsigned long long*)ws;
    if (ctl[3] == 0ull) return;
    constexpr int L = 2048, DK = 64, PAD = 72;
    constexpr float C1 = 0.18033688011112042f;   // 0.125 * log2(e)
    constexpr float C2 = -11.541560327111708f;   // -8 * log2(e)
    __shared__ __align__(16) u16 Ks[64 * PAD];
    __shared__ __align__(16) u16 Vs[64 * PAD];
    __shared__ __align__(16) u16 Pl[4 * 16 * PAD];
    u16* base = ws + 64;
    u16* vt   = ws + 64 + 7340032;
    u16* qb   = out;
    u16* kb   = out + 4194304;
    const int tid = threadIdx.x;
    const int wave = tid >> 6, lane = tid & 63;
    const int quad = lane >> 4, l16 = lane & 15;
    // 1024 blocks, model: xcd = bid&7, CU = (bid>>3)%32. Per (xcd,CU) the four
    // t=0..3 blocks get qt {31-c, c, 31-c', c'} (c'=(c+16)&31): per-CU work = 66
    // chunks exactly (balanced), 4 bh per XCD (L2-resident K/V, r5-verified).
    const int bid = (int)blockIdx.x;
    const int x = bid & 7, j = bid >> 3;
    const int t = j >> 5, c = j & 31;
    const int bh = x * 4 + t;
    const int c2 = (c + ((t >> 1) << 4)) & 31;
    const int qt = (t & 1) ? c2 : 31 - c2;
    const u16* Qp = qb + (size_t)bh * L * DK;
    const u16* Kp = kb + (size_t)bh * L * DK;
    const u16* Vp = vt + (size_t)bh * DK * L;
    u16* Pw = &Pl[wave * 16 * PAD];
    const int b = bh >> 4, h = bh & 15;
    const int srow = tid >> 3, scol = (tid & 7) * 8;

    const int q0 = qt * 64 + wave * 16;
    const bf16x8 qf0 = *(const bf16x8*)&Qp[(size_t)(q0 + l16) * DK + quad * 8];
    const bf16x8 qf1 = *(const bf16x8*)&Qp[(size_t)(q0 + l16) * DK + quad * 8 + 32];
    f32x4 oacc[4] = {};
    float lpart[4] = {0.f, 0.f, 0.f, 0.f};

    for (int kc = 0; kc <= qt; ++kc) {
        const int k0 = kc * 64;
        __syncthreads();  // Ks/Vs reuse from previous chunk
#pragma unroll
        for (int it = 0; it < 2; ++it) {
            const int r = srow + it * 32;
            *(int4*)&Ks[r * PAD + scol] = *(const int4*)&Kp[(size_t)(k0 + r) * DK + scol];
            *(int4*)&Vs[r * PAD + scol] = *(const int4*)&Vp[(size_t)r * L + k0 + scol];
        }
        __syncthreads();
        const bool maskchunk = (kc == qt);
        f32x4 sacc[4];
        __builtin_amdgcn_s_setprio(1);   // T5: favor MFMA vs co-resident blocks' loads
#pragma unroll
        for (int kt = 0; kt < 4; ++kt) {
            const bf16x8 kf0 = *(const bf16x8*)&Ks[(kt * 16 + l16) * PAD + quad * 8];
            const bf16x8 kf1 = *(const bf16x8*)&Ks[(kt * 16 + l16) * PAD + quad * 8 + 32];
            f32x4 z = {0.f, 0.f, 0.f, 0.f};
            z = MFMA16(qf0, kf0, z);
            sacc[kt] = MFMA16(qf1, kf1, z);
        }
        __builtin_amdgcn_s_setprio(0);
#pragma unroll
        for (int kt = 0; kt < 4; ++kt)
#pragma unroll
            for (int r = 0; r < 4; ++r) {
                float s = bfrd(sacc[kt][r]);           // native cvt (RNE, = bfround)
                if (maskchunk) {
                    const int key = k0 + kt * 16 + l16;
                    const int qrow = q0 + quad * 4 + r;
                    if (key > qrow) s = -3.0e38f;
                }
                const float pv = exp2f(__builtin_fmaf(s, C1, C2));  // exp(s/8 - 8)
                lpart[r] += pv;
                Pw[(quad * 4 + r) * PAD + kt * 16 + l16] = f2bf_n(pv);
            }
        // wave-private P region: lgkmcnt ordering suffices, no barrier
        const bf16x8 pa0 = *(const bf16x8*)&Pw[l16 * PAD + quad * 8];
        const bf16x8 pa1 = *(const bf16x8*)&Pw[l16 * PAD + quad * 8 + 32];
        __builtin_amdgcn_s_setprio(1);
#pragma unroll
        for (int nt = 0; nt < 4; ++nt) {
            const bf16x8 vf0 = *(const bf16x8*)&Vs[(nt * 16 + l16) * PAD + quad * 8];
            const bf16x8 vf1 = *(const bf16x8*)&Vs[(nt * 16 + l16) * PAD + quad * 8 + 32];
            oacc[nt] = MFMA16(pa0, vf0, oacc[nt]);
            oacc[nt] = MFMA16(pa1, vf1, oacc[nt]);
        }
        __builtin_amdgcn_s_setprio(0);
    }
    // reduce l over the 16 lanes holding this row's columns
    float linv[4];
#pragma unroll
    for (int r = 0; r < 4; ++r) {
        float ls = lpart[r];
#pragma unroll
        for (int off = 1; off < 16; off <<= 1) ls += __shfl_xor(ls, off);
        linv[r] = 1.0f / ls;
    }
#pragma unroll
    for (int nt = 0; nt < 4; ++nt)
#pragma unroll
        for (int r = 0; r < 4; ++r) {
            const int q = q0 + quad * 4 + r;
            base[((size_t)b * 2048 + q) * 1024 + h * 64 + nt * 16 + l16] =
                f2bf_n(oacc[nt][r] * linv[r]);
        }
}

// ---- out-proj GEMM (m97, BK=32, default map — proven) -> f32 d_out; failure fill ----
__global__ __launch_bounds__(256) void MultiHeadSelfAttention_11759620456627_outp(u16* out, u16* ws) {
    unsigned long long* ctl = (unsigned long long*)ws;
    const int tid = threadIdx.x;
    if (ctl[3] == 0ull) {  // failure-code fill of f32 d_out
        union { unsigned int u; float f; } cv; cv.u = (unsigned int)ctl[5];
        float* outf = (float*)(void*)out;
        const int bid = blockIdx.y * gridDim.x + blockIdx.x;
        for (int k = 0; k < 64; ++k)
            outf[(size_t)(bid * 256 + tid) + (size_t)k * 65536] = cv.f;
        return;
    }
    __shared__ __align__(16) u16 As[4096];   // 128 x 32 linear
    __shared__ __align__(16) u16 Bs[4096];
    const u16* A  = ws + 64;
    const u16* Bt = ws + 64 + 4194304;
    const int K = 1024;
    const int wave = tid >> 6, lane = tid & 63;
    const int quad = lane >> 4, l16 = lane & 15;
    const int m0 = blockIdx.y * 128, n0 = blockIdx.x * 128;
    const int wr = (wave >> 1) * 64, wc = (wave & 1) * 64;
    f32x4 acc[4][4] = {};
    const int rl = wave * 16 + (lane >> 2), cl = (lane & 3) * 8;
    const u16* a0 = A  + (size_t)(m0 + rl) * K + cl;
    const u16* a1 = A  + (size_t)(m0 + 64 + rl) * K + cl;
    const u16* b0 = Bt + (size_t)(n0 + rl) * K + cl;
    const u16* b1 = Bt + (size_t)(n0 + 64 + rl) * K + cl;
    u16* lA0 = As + wave * 512;
    u16* lA1 = As + 2048 + wave * 512;
    u16* lB0 = Bs + wave * 512;
    u16* lB1 = Bs + 2048 + wave * 512;
    for (int kb2 = 0; kb2 < K; kb2 += 32) {
        gload16(a0 + kb2, lA0);
        gload16(a1 + kb2, lA1);
        gload16(b0 + kb2, lB0);
        gload16(b1 + kb2, lB1);
        __syncthreads();
        bf16x8 af[4], bfr[4];
#pragma unroll
        for (int i = 0; i < 4; ++i) af[i] = *(const bf16x8*)&As[(wr + i * 16 + l16) * 32 + quad * 8];
#pragma unroll
        for (int j = 0; j < 4; ++j) bfr[j] = *(const bf16x8*)&Bs[(wc + j * 16 + l16) * 32 + quad * 8];
#pragma unroll
        for (int i = 0; i < 4; ++i)
#pragma unroll
            for (int j = 0; j < 4; ++j) acc[i][j] = MFMA16(af[i], bfr[j], acc[i][j]);
        __syncthreads();
    }
    float* outf = (float*)(void*)out;
#pragma unroll
    for (int i = 0; i < 4; ++i)
#pragma unroll
        for (int j = 0; j < 4; ++j) {
            const int col = n0 + wc + j * 16 + l16;
#pragma unroll
            for (int r = 0; r < 4; ++r) {
                const int row = m0 + wr + i * 16 + quad * 4 + r;
                outf[(size_t)row * 1024 + col] = bfround(acc[i][j][r]);
            }
        }
}

extern "C" void kernel_launch(void* const* d_in, const int* in_sizes, int n_in,
                              void* d_out, int out_size, void* d_ws, size_t ws_size,
                              hipStream_t stream) {
    (void)out_size;
    const u16* p[6] = {0, 0, 0, 0, 0, 0};
    int s[6] = {-1, -1, -1, -1, -1, -1};
    for (int i = 0; i < n_in && i < 6; ++i) { p[i] = (const u16*)d_in[i]; s[i] = in_sizes[i]; }
    u16* out = (u16*)d_out;
    u16* ws  = (u16*)d_ws;
    const unsigned long long wsbytes = (unsigned long long)ws_size;

    MultiHeadSelfAttention_11759620456627_init<<<dim3(1, 1), 256, 0, stream>>>(
        p[0], p[1], p[2], p[3], p[4], p[5], s[0], s[1], s[2], s[3], s[4], s[5],
        n_in, wsbytes, ws);
    MultiHeadSelfAttention_11759620456627_prep<<<dim3(2816, 1), 256, 0, stream>>>(ws);
    MultiHeadSelfAttention_11759620456627_qkv<<<dim3(24, 32), 256, 0, stream>>>(out, ws);
    MultiHeadSelfAttention_11759620456627_transw<<<dim3(16, 16), 256, 0, stream>>>(ws);
    MultiHeadSelfAttention_11759620456627_attn<<<dim3(1024, 1), 256, 0, stream>>>(out, ws);
    MultiHeadSelfAttention_11759620456627_outp<<<dim3(8, 32), 256, 0, stream>>>(out, ws);
}

// Round 19
// 225.256 us; speedup vs baseline: 1.0729x; 1.0106x over previous
//
#include <hip/hip_runtime.h>
#include <hip/hip_bf16.h>

typedef __bf16 bf16x8 __attribute__((ext_vector_type(8)));
typedef float f32x4 __attribute__((ext_vector_type(4)));
typedef unsigned short u16;

#define MFMA16(a, b, c) __builtin_amdgcn_mfma_f32_16x16x32_bf16((a), (b), (c), 0, 0, 0)

typedef __attribute__((address_space(1))) void glb_void;
typedef __attribute__((address_space(3))) void lds_void;

// async global->LDS, 16B per lane; LDS dest = wave-uniform base + lane*16
__device__ __forceinline__ void gload16(const void* g, void* l) {
    __builtin_amdgcn_global_load_lds((glb_void*)g, (lds_void*)l, 16, 0, 0);
}

__device__ __forceinline__ float bf2f(u16 h) {
    union { unsigned int u; float f; } v;
    v.u = ((unsigned int)h) << 16;
    return v.f;
}
__device__ __forceinline__ u16 f2bf(float f) {
    union { float f; unsigned int u; } v;
    v.f = f;
    unsigned int r = v.u + 0x7fffu + ((v.u >> 16) & 1u);
    return (u16)(r >> 16);
}
__device__ __forceinline__ float bfround(float f) { return bf2f(f2bf(f)); }
// native RNE f32->bf16 (v_cvt, bit-identical to f2bf for non-NaN) — attn hot loop
__device__ __forceinline__ u16 f2bf_n(float f) {
    union { __bf16 h; u16 u; } t; t.h = (__bf16)f; return t.u;
}
__device__ __forceinline__ float bfrd(float f) { return (float)(__bf16)f; }

// ws layout (u16 elems): [ctl 64][base: xb/ctx 4194304][wqkv_t/wout_t 3145728][Vt 4194304]
// d_out (16 MB f32): stages Qb (8 MB bf16) + Kb (8 MB bf16); final GEMM overwrites with f32.
// Base = quadruple-verified 227.4-228.8us config. r19 delta (attn map only): qt-pairing
// bijection — per CU lengths {32-c,31-c,2+c,1+c} (sum 66): longest block always has a
// near-equal partner -> solo tail 15 chunks -> 1 chunk (c=0); mid CUs {16,17,16,17}.
// Closed: GEMM BK=64 (r8/r12), attn pad 76 (r13), attn reg-prefetch (r5/r6/r15 spill),
// GEMM XCD swizzle (r17).

// ---- init: probe + bind + MFMA self-test, single 1-block kernel ----
__global__ __launch_bounds__(256) void MultiHeadSelfAttention_11759620456627_init(
    const u16* p0, const u16* p1, const u16* p2, const u16* p3, const u16* p4, const u16* p5,
    int s0, int s1, int s2, int s3, int s4, int s5,
    int n_in, unsigned long long wsbytes, u16* ws) {
    __shared__ unsigned long long sctl[6];
    __shared__ int flagv;
    __shared__ __align__(16) u16 At[512];
    __shared__ __align__(16) u16 Bt2[512];
    const int tid = threadIdx.x;
    if (tid == 0) flagv = 0;
    if (tid < 64) {
        const u16* ptrs[6] = {p0, p1, p2, p3, p4, p5};
        long long szs[6] = {s0, s1, s2, s3, s4, s5};
        int cls[6];
        const u16* xp = 0;
        int xf = 0, ncx = 0, ncw = 0;
        const u16* wp[2] = {0, 0};
        long long wsz[2] = {0, 0};
        int wf[2] = {0, 0};
        const size_t lane = (size_t)tid;
        for (int i = 0; i < 6; ++i) {
            cls[i] = 3;
            if (i >= n_in || ptrs[i] == 0 || szs[i] < 1048576) continue;  // wave-uniform
            u16 a = ptrs[i][lane * 8191 + 1];
            float fa = fabsf(bf2f(a));
            float vb = ((const float*)(const void*)ptrs[i])[lane * 4093 + 1];
            float fb = fabsf(vb);
            const int nmask  = __popcll(__ballot(a == 0 || a == 1 || a == 256 || a == 257 || a == 0x3F80));
            const int plausA = __popcll(__ballot(fa > 0.0005f && fa < 64.0f));
            const int plausB = __popcll(__ballot(fb > 0.0005f && fb < 64.0f));
            const int bigA   = __popcll(__ballot(fa >= 0.125f && fa < 64.0f));
            const int bigB   = __popcll(__ballot(fb >= 0.125f && fb < 64.0f));
            if (nmask >= 60) { cls[i] = 0; continue; }
            const int isf = (plausB > plausA) ? 1 : 0;
            const int big = isf ? bigB : bigA;
            if (big >= 16) { cls[i] = 2; xp = ptrs[i]; xf = isf; ++ncx; }
            else {
                cls[i] = 1;
                if (ncw < 2) { wp[ncw] = ptrs[i]; wsz[ncw] = szs[i]; wf[ncw] = isf; }
                ++ncw;
            }
        }
        if (tid == 0) {
            const u16 *wq = 0, *wo = 0;
            int qf = 0, of = 0, ok = 0;
            if (ncx == 1 && ncw == 2) {
                if (wsz[0] == 3 * wsz[1])      { wq = wp[0]; qf = wf[0]; wo = wp[1]; of = wf[1]; ok = 1; }
                else if (wsz[1] == 3 * wsz[0]) { wq = wp[1]; qf = wf[1]; wo = wp[0]; of = wf[0]; ok = 1; }
            }
            const int wsok = (wsbytes >= 128ull + 23068672ull) ? 1 : 0;
            if (!wsok) ok = 0;
            float code = 0.0f;
            if (!ok) {
                if (!wsok) code = 6144.0f;
                else if (ncx == 1 && ncw == 2) code = 5120.0f;
                else code = 2048.0f + 8.0f * (float)(cls[0] + 4 * cls[1] + 16 * cls[2] + 64 * cls[3]);
            }
            sctl[0] = (unsigned long long)xp;
            sctl[1] = (unsigned long long)wq;
            sctl[2] = (unsigned long long)wo;
            sctl[3] = (unsigned long long)ok;
            sctl[4] = (unsigned long long)(xf | (qf << 1) | (of << 2));
            union { float f; unsigned int u; } cv; cv.f = code;
            sctl[5] = (unsigned long long)cv.u;
        }
    }
    __syncthreads();
    const int okv = (sctl[3] != 0ull);
    if (okv) {   // MFMA self-test (block-uniform gate)
        if (tid < 64)
            for (int i = tid; i < 512; i += 64) {
                int m = i >> 5, k = i & 31;
                At[i]  = f2bf((float)((m * 3 + k) % 7 - 3) * 0.25f);
                Bt2[i] = f2bf((float)((m + 2 * k) % 5 - 2) * 0.25f);
            }
        __syncthreads();
        if (tid < 64) {
            const int l16 = tid & 15, quad = tid >> 4;
            bf16x8 a = *(bf16x8*)&At[l16 * 32 + quad * 8];
            bf16x8 b = *(bf16x8*)&Bt2[l16 * 32 + quad * 8];
            f32x4 c = {0.f, 0.f, 0.f, 0.f};
            c = MFMA16(a, b, c);
            for (int r = 0; r < 4; ++r) {
                const int row = quad * 4 + r, col = l16;
                float ref = 0.f;
                for (int k = 0; k < 32; ++k) ref += bf2f(At[row * 32 + k]) * bf2f(Bt2[col * 32 + k]);
                if (fabsf(c[r] - ref) > 1e-3f) { *(volatile int*)&flagv = 1; }
            }
        }
        __syncthreads();
    }
    if (tid == 0) {
        if (okv && flagv) {
            sctl[3] = 0ull;
            union { float f; unsigned int u; } cv; cv.f = 10240.0f;
            sctl[5] = (unsigned long long)cv.u;
        }
        unsigned long long* ctl = (unsigned long long*)ws;
        for (int i = 0; i < 6; ++i) ctl[i] = sctl[i];
    }
}

// ---- prep: convx (blocks 0..2047, f32 input only) + transpose Wqkv (blocks 2048..2815) ----
__global__ __launch_bounds__(256) void MultiHeadSelfAttention_11759620456627_prep(u16* ws) {
    unsigned long long* ctl = (unsigned long long*)ws;
    if (ctl[3] == 0ull) return;
    __shared__ __align__(16) u16 t[64][72];   // transw path only; pad 72 = 16B-aligned rows
    const int bid = (int)blockIdx.x;
    const int tid = threadIdx.x;
    if (bid < 2048) {   // convx: only needed for f32 input (bf16 read directly by qkv)
        const int xf = (int)(ctl[4] & 1ull);
        if (!xf) return;
        u16* base = ws + 64;
        const float* xp = (const float*)(const void*)ctl[0];
        const size_t i0 = ((size_t)(bid * 256 + tid)) * 8;
        float4 a = *(const float4*)&xp[i0];
        float4 bb = *(const float4*)&xp[i0 + 4];
        union { u16 h[8]; int4 v; } tv;
        tv.h[0] = f2bf(a.x);  tv.h[1] = f2bf(a.y);  tv.h[2] = f2bf(a.z);  tv.h[3] = f2bf(a.w);
        tv.h[4] = f2bf(bb.x); tv.h[5] = f2bf(bb.y); tv.h[6] = f2bf(bb.z); tv.h[7] = f2bf(bb.w);
        *(int4*)&base[i0] = tv.v;
        return;
    }
    // transw0: Wqkv (1024 x 3072) -> wqkv_t (3072 x 1024)
    const int idx = bid - 2048;
    const int bx = idx % 48, by = idx / 48;
    const u16* src = (const u16*)ctl[1];
    const int flag = (int)((ctl[4] >> 1) & 1ull);
    const int C = 3072, R = 1024;
    u16* dst = ws + 64 + 4194304;
    const int r0 = by * 64, c0 = bx * 64;
    for (int i = tid; i < 512; i += 256) {
        const int r = i >> 3, c8 = (i & 7) * 8;
        const size_t o = (size_t)(r0 + r) * C + c0 + c8;
        if (!flag) {
            *(int4*)&t[r][c8] = *(const int4*)&src[o];
        } else {
            const float* sf = (const float*)(const void*)src;
            float4 a = *(const float4*)&sf[o];
            float4 bb = *(const float4*)&sf[o + 4];
            u16* d = &t[r][c8];
            d[0] = f2bf(a.x);  d[1] = f2bf(a.y);  d[2] = f2bf(a.z);  d[3] = f2bf(a.w);
            d[4] = f2bf(bb.x); d[5] = f2bf(bb.y); d[6] = f2bf(bb.z); d[7] = f2bf(bb.w);
        }
    }
    __syncthreads();
    for (int i = tid; i < 512; i += 256) {
        const int r = i >> 3, c8 = (i & 7) * 8;
        union { u16 h[8]; int4 v; } tmp;
#pragma unroll
        for (int j = 0; j < 8; ++j) tmp.h[j] = t[c8 + j][r];
        *(int4*)&dst[(size_t)(c0 + r) * R + r0 + c8] = tmp.v;
    }
}

// ---- transpose Wout (1024x1024) -> wout_t; runs after qkv (reuses wqkv_t region) ----
__global__ __launch_bounds__(256) void MultiHeadSelfAttention_11759620456627_transw(u16* ws) {
    unsigned long long* ctl = (unsigned long long*)ws;
    if (ctl[3] == 0ull) return;
    __shared__ __align__(16) u16 t[64][72];
    const int tid = threadIdx.x;
    const u16* src = (const u16*)ctl[2];
    const int flag = (int)((ctl[4] >> 2) & 1ull);
    const int C = 1024, R = 1024;
    u16* dst = ws + 64 + 4194304;
    const int r0 = blockIdx.y * 64, c0 = blockIdx.x * 64;
    for (int idx = tid; idx < 512; idx += 256) {
        const int r = idx >> 3, c8 = (idx & 7) * 8;
        const size_t o = (size_t)(r0 + r) * C + c0 + c8;
        if (!flag) {
            *(int4*)&t[r][c8] = *(const int4*)&src[o];
        } else {
            const float* sf = (const float*)(const void*)src;
            float4 a = *(const float4*)&sf[o];
            float4 bb = *(const float4*)&sf[o + 4];
            u16* d = &t[r][c8];
            d[0] = f2bf(a.x);  d[1] = f2bf(a.y);  d[2] = f2bf(a.z);  d[3] = f2bf(a.w);
            d[4] = f2bf(bb.x); d[5] = f2bf(bb.y); d[6] = f2bf(bb.z); d[7] = f2bf(bb.w);
        }
    }
    __syncthreads();
    for (int idx = tid; idx < 512; idx += 256) {
        const int r = idx >> 3, c8 = (idx & 7) * 8;
        union { u16 h[8]; int4 v; } tmp;
#pragma unroll
        for (int j = 0; j < 8; ++j) tmp.h[j] = t[c8 + j][r];
        *(int4*)&dst[(size_t)(c0 + r) * R + r0 + c8] = tmp.v;
    }
}

// ---- qkv GEMM (m97 structure, BK=32, default block map — proven) + scatter ----
__global__ __launch_bounds__(256) void MultiHeadSelfAttention_11759620456627_qkv(u16* out, u16* ws) {
    unsigned long long* ctl = (unsigned long long*)ws;
    if (ctl[3] == 0ull) return;
    __shared__ __align__(16) u16 As[4096];   // 128 x 32 linear (gload_lds contract)
    __shared__ __align__(16) u16 Bs[4096];
    const int xf = (int)(ctl[4] & 1ull);
    const u16* A  = xf ? (ws + 64) : (const u16*)ctl[0];   // bf16 input: read x directly
    const u16* Bt = ws + 64 + 4194304;
    u16* vt = ws + 64 + 7340032;
    u16* qb = out;
    u16* kb = out + 4194304;
    const int K = 1024;
    const int tid = threadIdx.x;
    const int wave = tid >> 6, lane = tid & 63;
    const int quad = lane >> 4, l16 = lane & 15;
    const int m0 = blockIdx.y * 128, n0 = blockIdx.x * 128;
    const int wr = (wave >> 1) * 64, wc = (wave & 1) * 64;
    f32x4 acc[4][4] = {};
    const int rl = wave * 16 + (lane >> 2), cl = (lane & 3) * 8;
    const u16* a0 = A  + (size_t)(m0 + rl) * K + cl;
    const u16* a1 = A  + (size_t)(m0 + 64 + rl) * K + cl;
    const u16* b0 = Bt + (size_t)(n0 + rl) * K + cl;
    const u16* b1 = Bt + (size_t)(n0 + 64 + rl) * K + cl;
    u16* lA0 = As + wave * 512;
    u16* lA1 = As + 2048 + wave * 512;
    u16* lB0 = Bs + wave * 512;
    u16* lB1 = Bs + 2048 + wave * 512;
    for (int kb2 = 0; kb2 < K; kb2 += 32) {
        gload16(a0 + kb2, lA0);
        gload16(a1 + kb2, lA1);
        gload16(b0 + kb2, lB0);
        gload16(b1 + kb2, lB1);
        __syncthreads();               // drains vmcnt(0): LDS tiles complete
        bf16x8 af[4], bfr[4];
#pragma unroll
        for (int i = 0; i < 4; ++i) af[i] = *(const bf16x8*)&As[(wr + i * 16 + l16) * 32 + quad * 8];
#pragma unroll
        for (int j = 0; j < 4; ++j) bfr[j] = *(const bf16x8*)&Bs[(wc + j * 16 + l16) * 32 + quad * 8];
#pragma unroll
        for (int i = 0; i < 4; ++i)
#pragma unroll
            for (int j = 0; j < 4; ++j) acc[i][j] = MFMA16(af[i], bfr[j], acc[i][j]);
        __syncthreads();
    }
    // scatter: Q,K (BH,L,64) in d_out; V^T (BH,64,L) in ws
#pragma unroll
    for (int i = 0; i < 4; ++i)
#pragma unroll
        for (int j = 0; j < 4; ++j) {
            const int col = n0 + wc + j * 16 + l16;
            const int s = col >> 10, rem = col & 1023;
            const int h = rem >> 6, d = rem & 63;
#pragma unroll
            for (int r = 0; r < 4; ++r) {
                const int row = m0 + wr + i * 16 + quad * 4 + r;
                const int b = row >> 11, l = row & 2047;
                const int bh = b * 16 + h;
                const u16 val = f2bf(acc[i][j][r]);
                if (s == 0)      qb[((size_t)bh * 2048 + l) * 64 + d] = val;
                else if (s == 1) kb[((size_t)bh * 2048 + l) * 64 + d] = val;
                else             vt[((size_t)bh * 64 + d) * 2048 + l] = val;
            }
        }
}

// ---- flash attention: XCD map + long-long qt pairing + setprio, PAD=72 ----
__global__ __launch_bounds__(256) void MultiHeadSelfAttention_11759620456627_attn(u16* out, u16* ws) {
    unsigned long long* ctl = (unsigned long long*)ws;
    if (ctl[3] == 0ull) return;
    constexpr int L = 2048, DK = 64, PAD = 72;
    constexpr float C1 = 0.18033688011112042f;   // 0.125 * log2(e)
    constexpr float C2 = -11.541560327111708f;   // -8 * log2(e)
    __shared__ __align__(16) u16 Ks[64 * PAD];
    __shared__ __align__(16) u16 Vs[64 * PAD];
    __shared__ __align__(16) u16 Pl[4 * 16 * PAD];
    u16* base = ws + 64;
    u16* vt   = ws + 64 + 7340032;
    u16* qb   = out;
    u16* kb   = out + 4194304;
    const int tid = threadIdx.x;
    const int wave = tid >> 6, lane = tid & 63;
    const int quad = lane >> 4, l16 = lane & 15;
    // 1024 blocks; dispatch model xcd = bid&7, CU = (bid>>3)%32 (r2/r5/r8-verified).
    // qt map (r19): CU c gets lengths {32-c, 31-c, 2+c, 1+c} (sum 66 for every c) —
    // the longest block always runs 2-way with a near-equal partner (solo tail 15->1
    // chunk at c=0; mid CUs {16,17,16,17} never solo). Bijective per t: 31-c, (30-c)&31,
    // (1+c)&31, c.
    const int bid = (int)blockIdx.x;
    const int x = bid & 7, j = bid >> 3;
    const int t = j >> 5, c = j & 31;
    const int bh = x * 4 + t;
    int qt;
    if      (t == 0) qt = 31 - c;
    else if (t == 1) qt = (30 - c) & 31;
    else if (t == 2) qt = (1 + c) & 31;
    else             qt = c;
    const u16* Qp = qb + (size_t)bh * L * DK;
    const u16* Kp = kb + (size_t)bh * L * DK;
    const u16* Vp = vt + (size_t)bh * DK * L;
    u16* Pw = &Pl[wave * 16 * PAD];
    const int b = bh >> 4, h = bh & 15;
    const int srow = tid >> 3, scol = (tid & 7) * 8;

    const int q0 = qt * 64 + wave * 16;
    const bf16x8 qf0 = *(const bf16x8*)&Qp[(size_t)(q0 + l16) * DK + quad * 8];
    const bf16x8 qf1 = *(const bf16x8*)&Qp[(size_t)(q0 + l16) * DK + quad * 8 + 32];
    f32x4 oacc[4] = {};
    float lpart[4] = {0.f, 0.f, 0.f, 0.f};

    for (int kc = 0; kc <= qt; ++kc) {
        const int k0 = kc * 64;
        __syncthreads();  // Ks/Vs reuse from previous chunk
#pragma unroll
        for (int it = 0; it < 2; ++it) {
            const int r = srow + it * 32;
            *(int4*)&Ks[r * PAD + scol] = *(const int4*)&Kp[(size_t)(k0 + r) * DK + scol];
            *(int4*)&Vs[r * PAD + scol] = *(const int4*)&Vp[(size_t)r * L + k0 + scol];
        }
        __syncthreads();
        const bool maskchunk = (kc == qt);
        f32x4 sacc[4];
        __builtin_amdgcn_s_setprio(1);   // T5: favor MFMA vs co-resident blocks' loads
#pragma unroll
        for (int kt = 0; kt < 4; ++kt) {
            const bf16x8 kf0 = *(const bf16x8*)&Ks[(kt * 16 + l16) * PAD + quad * 8];
            const bf16x8 kf1 = *(const bf16x8*)&Ks[(kt * 16 + l16) * PAD + quad * 8 + 32];
            f32x4 z = {0.f, 0.f, 0.f, 0.f};
            z = MFMA16(qf0, kf0, z);
            sacc[kt] = MFMA16(qf1, kf1, z);
        }
        __builtin_amdgcn_s_setprio(0);
#pragma unroll
        for (int kt = 0; kt < 4; ++kt)
#pragma unroll
            for (int r = 0; r < 4; ++r) {
                float s = bfrd(sacc[kt][r]);           // native cvt (RNE, = bfround)
                if (maskchunk) {
                    const int key = k0 + kt * 16 + l16;
                    const int qrow = q0 + quad * 4 + r;
                    if (key > qrow) s = -3.0e38f;
                }
                const float pv = exp2f(__builtin_fmaf(s, C1, C2));  // exp(s/8 - 8)
                lpart[r] += pv;
                Pw[(quad * 4 + r) * PAD + kt * 16 + l16] = f2bf_n(pv);
            }
        // wave-private P region: lgkmcnt ordering suffices, no barrier
        const bf16x8 pa0 = *(const bf16x8*)&Pw[l16 * PAD + quad * 8];
        const bf16x8 pa1 = *(const bf16x8*)&Pw[l16 * PAD + quad * 8 + 32];
        __builtin_amdgcn_s_setprio(1);
#pragma unroll
        for (int nt = 0; nt < 4; ++nt) {
            const bf16x8 vf0 = *(const bf16x8*)&Vs[(nt * 16 + l16) * PAD + quad * 8];
            const bf16x8 vf1 = *(const bf16x8*)&Vs[(nt * 16 + l16) * PAD + quad * 8 + 32];
            oacc[nt] = MFMA16(pa0, vf0, oacc[nt]);
            oacc[nt] = MFMA16(pa1, vf1, oacc[nt]);
        }
        __builtin_amdgcn_s_setprio(0);
    }
    // reduce l over the 16 lanes holding this row's columns
    float linv[4];
#pragma unroll
    for (int r = 0; r < 4; ++r) {
        float ls = lpart[r];
#pragma unroll
        for (int off = 1; off < 16; off <<= 1) ls += __shfl_xor(ls, off);
        linv[r] = 1.0f / ls;
    }
#pragma unroll
    for (int nt = 0; nt < 4; ++nt)
#pragma unroll
        for (int r = 0; r < 4; ++r) {
            const int q = q0 + quad * 4 + r;
            base[((size_t)b * 2048 + q) * 1024 + h * 64 + nt * 16 + l16] =
                f2bf_n(oacc[nt][r] * linv[r]);
        }
}

// ---- out-proj GEMM (m97, BK=32, default map — proven) -> f32 d_out; failure fill ----
__global__ __launch_bounds__(256) void MultiHeadSelfAttention_11759620456627_outp(u16* out, u16* ws) {
    unsigned long long* ctl = (unsigned long long*)ws;
    const int tid = threadIdx.x;
    if (ctl[3] == 0ull) {  // failure-code fill of f32 d_out
        union { unsigned int u; float f; } cv; cv.u = (unsigned int)ctl[5];
        float* outf = (float*)(void*)out;
        const int bid = blockIdx.y * gridDim.x + blockIdx.x;
        for (int k = 0; k < 64; ++k)
            outf[(size_t)(bid * 256 + tid) + (size_t)k * 65536] = cv.f;
        return;
    }
    __shared__ __align__(16) u16 As[4096];   // 128 x 32 linear
    __shared__ __align__(16) u16 Bs[4096];
    const u16* A  = ws + 64;
    const u16* Bt = ws + 64 + 4194304;
    const int K = 1024;
    const int wave = tid >> 6, lane = tid & 63;
    const int quad = lane >> 4, l16 = lane & 15;
    const int m0 = blockIdx.y * 128, n0 = blockIdx.x * 128;
    const int wr = (wave >> 1) * 64, wc = (wave & 1) * 64;
    f32x4 acc[4][4] = {};
    const int rl = wave * 16 + (lane >> 2), cl = (lane & 3) * 8;
    const u16* a0 = A  + (size_t)(m0 + rl) * K + cl;
    const u16* a1 = A  + (size_t)(m0 + 64 + rl) * K + cl;
    const u16* b0 = Bt + (size_t)(n0 + rl) * K + cl;
    const u16* b1 = Bt + (size_t)(n0 + 64 + rl) * K + cl;
    u16* lA0 = As + wave * 512;
    u16* lA1 = As + 2048 + wave * 512;
    u16* lB0 = Bs + wave * 512;
    u16* lB1 = Bs + 2048 + wave * 512;
    for (int kb2 = 0; kb2 < K; kb2 += 32) {
        gload16(a0 + kb2, lA0);
        gload16(a1 + kb2, lA1);
        gload16(b0 + kb2, lB0);
        gload16(b1 + kb2, lB1);
        __syncthreads();
        bf16x8 af[4], bfr[4];
#pragma unroll
        for (int i = 0; i < 4; ++i) af[i] = *(const bf16x8*)&As[(wr + i * 16 + l16) * 32 + quad * 8];
#pragma unroll
        for (int j = 0; j < 4; ++j) bfr[j] = *(const bf16x8*)&Bs[(wc + j * 16 + l16) * 32 + quad * 8];
#pragma unroll
        for (int i = 0; i < 4; ++i)
#pragma unroll
            for (int j = 0; j < 4; ++j) acc[i][j] = MFMA16(af[i], bfr[j], acc[i][j]);
        __syncthreads();
    }
    float* outf = (float*)(void*)out;
#pragma unroll
    for (int i = 0; i < 4; ++i)
#pragma unroll
        for (int j = 0; j < 4; ++j) {
            const int col = n0 + wc + j * 16 + l16;
#pragma unroll
            for (int r = 0; r < 4; ++r) {
                const int row = m0 + wr + i * 16 + quad * 4 + r;
                outf[(size_t)row * 1024 + col] = bfround(acc[i][j][r]);
            }
        }
}

extern "C" void kernel_launch(void* const* d_in, const int* in_sizes, int n_in,
                              void* d_out, int out_size, void* d_ws, size_t ws_size,
                              hipStream_t stream) {
    (void)out_size;
    const u16* p[6] = {0, 0, 0, 0, 0, 0};
    int s[6] = {-1, -1, -1, -1, -1, -1};
    for (int i = 0; i < n_in && i < 6; ++i) { p[i] = (const u16*)d_in[i]; s[i] = in_sizes[i]; }
    u16* out = (u16*)d_out;
    u16* ws  = (u16*)d_ws;
    const unsigned long long wsbytes = (unsigned long long)ws_size;

    MultiHeadSelfAttention_11759620456627_init<<<dim3(1, 1), 256, 0, stream>>>(
        p[0], p[1], p[2], p[3], p[4], p[5], s[0], s[1], s[2], s[3], s[4], s[5],
        n_in, wsbytes, ws);
    MultiHeadSelfAttention_11759620456627_prep<<<dim3(2816, 1), 256, 0, stream>>>(ws);
    MultiHeadSelfAttention_11759620456627_qkv<<<dim3(24, 32), 256, 0, stream>>>(out, ws);
    MultiHeadSelfAttention_11759620456627_transw<<<dim3(16, 16), 256, 0, stream>>>(ws);
    MultiHeadSelfAttention_11759620456627_attn<<<dim3(1024, 1), 256, 0, stream>>>(out, ws);
    MultiHeadSelfAttention_11759620456627_outp<<<dim3(8, 32), 256, 0, stream>>>(out, ws);
}